// Round 1
// 201.470 us; speedup vs baseline: 1.0598x; 1.0598x over previous
//
#include <hip/hip_runtime.h>

// MV_GCN on MI355X — round 3: fuse K1+K2 via GEMM reassociation.
//   out = A_hat @ (X @ W)  ==  (A_hat @ X) @ W      (fp32 rounding differs)
// One block per (g,v): build A_hat in LDS from edges, M = A_hat @ X with X
// streamed per-lane from global, overwrite the SAME LDS buffer with M, then
// out = M @ W + b (W streamed per-lane, double-buffered), channel-max.
// LDS = 116*116*4 + dinv = 54.3 KB -> 2 blocks/CU (16 waves), no H HBM trip.

#define NB 256
#define NODES 116
#define FEAT 115
#define LENN 6670
#define SEG2 13456
#define HID 128
#define HC 512
#define ASTR 116   // compact row stride (464 B rows, 16 B aligned: 464 = 29*16)

__global__ __launch_bounds__(512, 4) void k_fused(
    const float* __restrict__ x, const int* __restrict__ ei,
    const float* __restrict__ ew,
    const float* __restrict__ W1, const float* __restrict__ b1,
    const float* __restrict__ W2, const float* __restrict__ b2,
    float* __restrict__ featws)
{
  __shared__ __align__(16) float sA[NODES * ASTR];   // A_hat, then M = A_hat@X
  __shared__ float dinv[NODES];
  const int bid = blockIdx.x;
  const int g = bid >> 1, v = bid & 1;
  const int tid = threadIdx.x;

  // ---- phase 0: zero A (116*116 = 13456 floats = 3364 float4, exact)
  const float4 z4 = make_float4(0.f, 0.f, 0.f, 0.f);
  for (int i = tid; i < (NODES * ASTR) / 4; i += 512) ((float4*)sA)[i] = z4;
  __syncthreads();

  // ---- phase 1: scatter edges  A_raw[d][s] += w  (int2/float2: eoff even)
  const int eoff = g * SEG2 + v * LENN;
  const int nbase = g * 232 + v * 116;
  const int* __restrict__ srcp = ei + eoff;
  const int* __restrict__ dstp = ei + (size_t)NB * SEG2 + eoff;
  const float* __restrict__ wp = ew + eoff;
#pragma unroll 2
  for (int q = tid; q < (LENN / 2); q += 512) {
    int2 s2 = ((const int2*)srcp)[q];
    int2 d2 = ((const int2*)dstp)[q];
    float2 w2 = ((const float2*)wp)[q];
    atomicAdd(&sA[(d2.x - nbase) * ASTR + (s2.x - nbase)], w2.x);
    atomicAdd(&sA[(d2.y - nbase) * ASTR + (s2.y - nbase)], w2.y);
  }
  __syncthreads();

  // ---- phase 2: deg via row sums (4 threads/row, stride-29 starts)
  if (tid < 4 * NODES) {
    const int r = tid >> 2, q = tid & 3;
    const float* row = &sA[r * ASTR + q * 29];
    float s = 0.f;
#pragma unroll
    for (int j = 0; j < 29; ++j) s += row[j];
    s += __shfl_xor(s, 1, 64);
    s += __shfl_xor(s, 2, 64);
    if (q == 0) dinv[r] = rsqrtf(s + 1.0f);   // deg + 1 self-loop
  }
  __syncthreads();

  // ---- phase 3: normalize in place; fold self-loop dinv^2 into diagonal
  for (int idx = tid; idx < NODES * NODES; idx += 512) {
    int d = idx / NODES;
    int s = idx - d * NODES;
    float di = dinv[d];
    float val = sA[idx] * (di * dinv[s]);
    if (d == s) val += di * di;
    sA[idx] = val;
  }
  __syncthreads();

  // ---- phase 4: M = A_hat(LDS, wave-uniform f4) @ X(global per-lane, dbuf)
  const int cg = tid & 63, rg = tid >> 6;
  const int c0 = cg * 2;
  const float* __restrict__ Xg = x + (size_t)nbase * FEAT;
  const bool p0 = (c0 < FEAT);
  const bool p1 = (c0 + 1 < FEAT);

  float2 macc[15];
#pragma unroll
  for (int i = 0; i < 15; ++i) macc[i] = make_float2(0.f, 0.f);

  float2 xc[4], xn[4];
#pragma unroll
  for (int j = 0; j < 4; ++j) {
    xn[j].x = p0 ? Xg[(size_t)j * FEAT + c0] : 0.f;
    xn[j].y = p1 ? Xg[(size_t)j * FEAT + c0 + 1] : 0.f;
  }

  for (int sc = 0; sc < 29; ++sc) {          // K = 116 nodes, 29*4 exact
#pragma unroll
    for (int j = 0; j < 4; ++j) xc[j] = xn[j];
    if (sc < 28) {
      const int sn = 4 * (sc + 1);
#pragma unroll
      for (int j = 0; j < 4; ++j) {
        xn[j].x = p0 ? Xg[(size_t)(sn + j) * FEAT + c0] : 0.f;
        xn[j].y = p1 ? Xg[(size_t)(sn + j) * FEAT + c0 + 1] : 0.f;
      }
    }
    const int s0 = 4 * sc;
#pragma unroll
    for (int i = 0; i < 15; ++i) {
      int r = rg + 8 * i;
      r = (r < NODES) ? r : (NODES - 1);
      float4 a = *(const float4*)&sA[r * ASTR + s0];  // wave-uniform bcast
      macc[i].x = fmaf(a.x, xc[0].x, macc[i].x);
      macc[i].x = fmaf(a.y, xc[1].x, macc[i].x);
      macc[i].x = fmaf(a.z, xc[2].x, macc[i].x);
      macc[i].x = fmaf(a.w, xc[3].x, macc[i].x);
      macc[i].y = fmaf(a.x, xc[0].y, macc[i].y);
      macc[i].y = fmaf(a.y, xc[1].y, macc[i].y);
      macc[i].y = fmaf(a.z, xc[2].y, macc[i].y);
      macc[i].y = fmaf(a.w, xc[3].y, macc[i].y);
    }
  }
  __syncthreads();   // everyone done reading A_hat

  // ---- phase 5: M overwrites sA (cols 0..115; col 115 == 0 from X pad)
  if (c0 < NODES) {
#pragma unroll
    for (int i = 0; i < 15; ++i) {
      int r = rg + 8 * i;
      r = (r < NODES) ? r : (NODES - 1);   // duplicate rows store same value
      *(float2*)&sA[r * ASTR + c0] = macc[i];
    }
  }
  __syncthreads();

  // ---- phase 6: out = M(LDS, wave-uniform f4) @ W(global per-lane, dbuf) + b
  const float* __restrict__ W = v ? W2 : W1;
  const float* __restrict__ bv = v ? b2 : b1;
  const float* __restrict__ Wc = W + c0;

  float2 bb = *(const float2*)(bv + c0);
  float2 acc[15];
#pragma unroll
  for (int i = 0; i < 15; ++i) acc[i] = bb;

  float2 wc[4], wn[4];
#pragma unroll
  for (int j = 0; j < 4; ++j) wn[j] = *(const float2*)(Wc + (size_t)j * HID);

  for (int kc = 0; kc < 29; ++kc) {          // k = 0..115 (M col 115 = 0)
#pragma unroll
    for (int j = 0; j < 4; ++j) wc[j] = wn[j];
    if (kc < 27) {
      const int kn = 4 * (kc + 1);
#pragma unroll
      for (int j = 0; j < 4; ++j)
        wn[j] = *(const float2*)(Wc + (size_t)(kn + j) * HID);
    } else if (kc == 27) {                   // tail rows 112..114 + zero row
#pragma unroll
      for (int j = 0; j < 3; ++j)
        wn[j] = *(const float2*)(Wc + (size_t)(112 + j) * HID);
      wn[3] = make_float2(0.f, 0.f);
    }
    const int k0 = 4 * kc;
#pragma unroll
    for (int i = 0; i < 15; ++i) {
      int r = rg + 8 * i;
      r = (r < NODES) ? r : (NODES - 1);
      float4 a = *(const float4*)&sA[r * ASTR + k0];  // wave-uniform bcast
      acc[i].x = fmaf(a.x, wc[0].x, acc[i].x);
      acc[i].x = fmaf(a.y, wc[1].x, acc[i].x);
      acc[i].x = fmaf(a.z, wc[2].x, acc[i].x);
      acc[i].x = fmaf(a.w, wc[3].x, acc[i].x);
      acc[i].y = fmaf(a.x, wc[0].y, acc[i].y);
      acc[i].y = fmaf(a.y, wc[1].y, acc[i].y);
      acc[i].y = fmaf(a.z, wc[2].y, acc[i].y);
      acc[i].y = fmaf(a.w, wc[3].y, acc[i].y);
    }
  }

  // ---- phase 7: channel max across the wave (2 channels/lane)
#pragma unroll
  for (int i = 0; i < 15; ++i) {
    int r = rg + 8 * i;
    r = (r < NODES) ? r : (NODES - 1);
    float m = fmaxf(acc[i].x, acc[i].y);
#pragma unroll
    for (int off = 32; off >= 1; off >>= 1)
      m = fmaxf(m, __shfl_xor(m, off, 64));
    if (cg == 0)
      featws[g * 232 + 2 * r + v] = m;   // stack([x1,x2],1).reshape
  }
}

// ---------------- K3: MLP  relu(feat@W6+b6)@W7+b7 ----------------
__global__ __launch_bounds__(512) void k_mlp(
    const float* __restrict__ featws, const float* __restrict__ W6,
    const float* __restrict__ b6, const float* __restrict__ W7,
    const float* __restrict__ b7, float* __restrict__ out)
{
  __shared__ float sf[232];
  __shared__ float red[8];
  const int g = blockIdx.x, tid = threadIdx.x;
  if (tid < 232) sf[tid] = featws[g * 232 + tid];
  __syncthreads();

  float a = b6[tid];
  const float* __restrict__ w6p = W6 + tid;
#pragma unroll 8
  for (int k = 0; k < 232; ++k)
    a = fmaf(sf[k], w6p[(size_t)k * HC], a);
  a = fmaxf(a, 0.f);
  float p = a * W7[tid];
#pragma unroll
  for (int off = 32; off >= 1; off >>= 1) p += __shfl_xor(p, off, 64);
  if ((tid & 63) == 0) red[tid >> 6] = p;
  __syncthreads();
  if (tid == 0) {
    float t = b7[0];
#pragma unroll
    for (int i = 0; i < 8; ++i) t += red[i];
    out[g] = t;
  }
}

extern "C" void kernel_launch(void* const* d_in, const int* in_sizes, int n_in,
                              void* d_out, int out_size, void* d_ws, size_t ws_size,
                              hipStream_t stream)
{
  const float* x  = (const float*)d_in[0];
  const int*   ei = (const int*)d_in[1];
  const float* ew = (const float*)d_in[2];
  // d_in[3] = batch (unused by reference)
  const float* W1 = (const float*)d_in[4];
  const float* b1 = (const float*)d_in[5];
  const float* W2 = (const float*)d_in[6];
  const float* b2 = (const float*)d_in[7];
  const float* W6 = (const float*)d_in[8];
  const float* b6 = (const float*)d_in[9];
  const float* W7 = (const float*)d_in[10];
  const float* b7 = (const float*)d_in[11];

  float* featws = (float*)d_ws;                 // 256*232 f32
  float* out    = (float*)d_out;

  hipLaunchKernelGGL(k_fused, dim3(2 * NB), dim3(512), 0, stream,
                     x, ei, ew, W1, b1, W2, b2, featws);
  hipLaunchKernelGGL(k_mlp,   dim3(NB),     dim3(512), 0, stream,
                     featws, W6, b6, W7, b7, out);
}